// Round 6
// baseline (575.044 us; speedup 1.0000x reference)
//
#include <hip/hip_runtime.h>
#include <hip/hip_bf16.h>
#include <hip/hip_fp16.h>

typedef _Float16 f16;
typedef _Float16 f16x8 __attribute__((ext_vector_type(8)));
typedef float f32x16 __attribute__((ext_vector_type(16)));
typedef unsigned int u32;

// Problem sizes (fixed)
#define BB 32
#define SS 2048
#define HH 1024
#define KK 1024

// ws layout (bytes)
#define WS_BP 0                            // packed Wv fp16: 2 MB
#define WS_HQ (2u*1024u*1024u)             // hq fp32: 32*1024*4 = 128 KB
#define WS_LP (WS_HQ + 131072u)            // logits partials: 4*32*2048*4 = 1 MB

__device__ __forceinline__ float tanh_f(float x) {
    // tanh(x) = 1 - 2/(e^{2x}+1); safe at +/-inf of exp
    float e = __expf(2.0f * x);
    return 1.0f - 2.0f * __builtin_amdgcn_rcpf(e + 1.0f);
}

// 8 fp32 -> f16x8 (compiler emits v_cvt_pkrtz_f16_f32 x4)
__device__ __forceinline__ f16x8 cvt8(float4 va, float4 vb) {
    union { f16 h[8]; f16x8 v; } u;
    u.h[0] = (f16)va.x; u.h[1] = (f16)va.y; u.h[2] = (f16)va.z; u.h[3] = (f16)va.w;
    u.h[4] = (f16)vb.x; u.h[5] = (f16)vb.y; u.h[6] = (f16)vb.z; u.h[7] = (f16)vb.w;
    return u.v;
}

// ---------------------------------------------------------------------------
// Pack Wv [k][n] fp32 -> fragment-ordered fp16 for mfma_f32_32x32x16_f16 B-operand,
// grouped so each (N-block, BK=32 K-iter) slice is one contiguous 16 KB chunk:
// BP[ntb(4)][kit(32)][ntl(8)][ksl(2)][lane(64)][j(8)]
// frag layout: B[k][n], lane l: n = l&31, k = ks*16 + (l>>5)*8 + j
__global__ void pack_wv(const float* __restrict__ Wv, f16* __restrict__ BP) {
    int i = blockIdx.x * 256 + threadIdx.x;   // i = k*1024 + n
    int k = i >> 10, n = i & 1023;
    float v = Wv[i];
    int ntb = n >> 8;              // N-block (256 cols)
    int ntl = (n >> 5) & 7;        // local 32-col tile
    int kit = k >> 5;              // K-iter (BK=32)
    int ksl = (k >> 4) & 1;        // local k-step
    int lane = ((k >> 3) & 1) * 32 + (n & 31);
    int j = k & 7;
    BP[((((ntb * 32 + kit) * 8 + ntl) * 2 + ksl) * 64 + lane) * 8 + j] = (f16)v;
}

// ---------------------------------------------------------------------------
// hq = query @ Wq + bq  (fp32). K split 4 ways, atomicAdd combine.
__global__ void hq_kernel(const float* __restrict__ query, const float* __restrict__ Wq,
                          const float* __restrict__ bq, float* __restrict__ hq) {
    int b = blockIdx.y;
    int h = (blockIdx.x & 3) * 256 + threadIdx.x;
    int v0 = (blockIdx.x >> 2) * 256;
    float acc = 0.f;
#pragma unroll 8
    for (int v = 0; v < 256; ++v)
        acc += query[b * 1024 + v0 + v] * Wq[(v0 + v) * 1024 + h];
    if (v0 == 0) acc += bq[h];
    atomicAdd(&hq[b * 1024 + h], acc);
}

// ---------------------------------------------------------------------------
// Fused 64x256x(K=1024) GEMM tile + tanh(hq+hv)·w row-reduction.
// BARRIER-FREE main loop: all operands straight from global memory to
// registers (B is L2-resident fragment-packed Wv; A's MFMA fragment layout is
// naturally 32B-contiguous per lane, one 128B line per row per iter per wave
// -> wn-duplication L1-absorbed, ntb-duplication XCD-L2-absorbed).
// 4 waves (256 thr) per block, wave tile 64x64 (2mt x 2nt), acc 64 VGPR,
// 3 waves/SIMD. No LDS, no __syncthreads until the tiny epilogue reduce.
__launch_bounds__(256, 3)
__global__ void fused_main(const float* __restrict__ value, const f16* __restrict__ BP,
                           const float* __restrict__ hq, const float* __restrict__ wvec,
                           float* __restrict__ lpart) {
    __shared__ float part[256];                // [wn(4)][row(64)]

    int bid = blockIdx.x;
    int tile = (bid & 7) * 512 + (bid >> 3);   // XCD-chunked swizzle (4096 % 8 == 0)
    int Mt = tile >> 2, ntb = tile & 3;        // 4 N-blocks of one M-tile co-XCD
    int m0 = Mt << 6;                          // 64 rows
    int b = m0 >> 11, s0 = m0 & 2047;

    int tid = threadIdx.x;
    int wn = tid >> 6, l = tid & 63;
    int l31 = l & 31, lg = l >> 5;

    // A: lane reads rows m0 + mt*32 + l31, 8 fp32 at k = t*32 + ks*16 + lg*8
    const float* aA = value + (size_t)(m0 + l31) * 1024 + lg * 8;
    // B: fragment-packed; frag(nt,ks) of iter t at +t*16384 + (wn*2+nt)*2048 + ks*1024
    const char* bB = (const char*)BP + (size_t)ntb * 524288 + (wn * 2) * 2048 + (size_t)l * 16;

    const f32x16 fzero = {};
    f32x16 acc[2][2];
#pragma unroll
    for (int mt = 0; mt < 2; ++mt)
#pragma unroll
        for (int nt = 0; nt < 2; ++nt) acc[mt][nt] = fzero;

#pragma unroll 1
    for (int t = 0; t < 32; ++t) {
        // ---- A loads: 8x dwordx4 (independent, issued together)
        float4 ax[2][2], ay[2][2];
        const float* at = aA + t * 32;
#pragma unroll
        for (int mt = 0; mt < 2; ++mt)
#pragma unroll
            for (int ks = 0; ks < 2; ++ks) {
                const float4* p = (const float4*)(at + mt * 32768 + ks * 16);
                ax[mt][ks] = p[0];
                ay[mt][ks] = p[1];
            }
        // ---- B loads: 4x dwordx4, perfectly coalesced, L2-resident
        const f16x8* bp = (const f16x8*)(bB + (size_t)t * 16384);
        f16x8 bv[2][2];
#pragma unroll
        for (int nt = 0; nt < 2; ++nt)
#pragma unroll
            for (int ks = 0; ks < 2; ++ks)
                bv[nt][ks] = bp[nt * 128 + ks * 64];    // f16x8 units: 2048B/16, 1024B/16
        // ---- cvt fp32 -> f16 fragments
        f16x8 av[2][2];
#pragma unroll
        for (int mt = 0; mt < 2; ++mt)
#pragma unroll
            for (int ks = 0; ks < 2; ++ks)
                av[mt][ks] = cvt8(ax[mt][ks], ay[mt][ks]);
        // ---- 8 MFMA
#pragma unroll
        for (int ks = 0; ks < 2; ++ks)
#pragma unroll
            for (int mt = 0; mt < 2; ++mt)
#pragma unroll
                for (int nt = 0; nt < 2; ++nt)
                    acc[mt][nt] = __builtin_amdgcn_mfma_f32_32x32x16_f16(
                        av[mt][ks], bv[nt][ks], acc[mt][nt], 0, 0, 0);
    }

    // ---- epilogue: t = tanh(hq + hv) * w, pair-folded col reduction
    int h0 = ntb * 256 + wn * 64 + l31;   // nt = 0
    int h1 = h0 + 32;                     // nt = 1
    float hq0 = hq[b * 1024 + h0], hq1 = hq[b * 1024 + h1];
    float w0 = wvec[h0], w1 = wvec[h1];

#pragma unroll
    for (int mt = 0; mt < 2; ++mt) {
#pragma unroll
        for (int i = 0; i < 8; ++i) {
            float pa = tanh_f(hq0 + acc[mt][0][2 * i]) * w0
                     + tanh_f(hq1 + acc[mt][1][2 * i]) * w1;
            float pb = tanh_f(hq0 + acc[mt][0][2 * i + 1]) * w0
                     + tanh_f(hq1 + acc[mt][1][2 * i + 1]) * w1;
            float ea = __shfl_xor(pa, 1), eb = __shfl_xor(pb, 1);
            float g = (l & 1) ? (pb + eb) : (pa + ea);
            g += __shfl_xor(g, 2); g += __shfl_xor(g, 4);
            g += __shfl_xor(g, 8); g += __shfl_xor(g, 16);
            if (l31 < 2) {
                int r = 2 * i + (l31 & 1);
                int row = mt * 32 + (r & 3) + ((r >> 2) << 3) + (lg << 2);
                part[wn * 64 + row] = g;
            }
        }
    }
    __syncthreads();
    if (tid < 64) {
        float s = part[tid] + part[64 + tid] + part[128 + tid] + part[192 + tid];
        lpart[((size_t)ntb * 32 + b) * 2048 + s0 + tid] = s;
    }
}

// ---------------------------------------------------------------------------
// Masked softmax over S=2048 per b, summing the 4 N-block logit partials.
__global__ void softmax_kernel(const float* __restrict__ lp, const int* __restrict__ mask,
                               float* __restrict__ out) {
    __shared__ float redm[16];
    __shared__ float reds[16];
    const int P = 32 * 2048;
    int b = blockIdx.x, t = threadIdx.x;
    int wid = t >> 6, lane = t & 63;
    int i0 = b * 2048 + t, i1 = i0 + 1024;
    float l0 = lp[i0] + lp[P + i0] + lp[2 * P + i0] + lp[3 * P + i0];
    float l1 = lp[i1] + lp[P + i1] + lp[2 * P + i1] + lp[3 * P + i1];
    float a0 = mask[i0] ? l0 : -1e9f;
    float a1 = mask[i1] ? l1 : -1e9f;
    float mx = fmaxf(a0, a1);
#pragma unroll
    for (int off = 1; off < 64; off <<= 1) mx = fmaxf(mx, __shfl_xor(mx, off));
    if (lane == 0) redm[wid] = mx;
    __syncthreads();
    mx = redm[0];
#pragma unroll
    for (int i = 1; i < 16; ++i) mx = fmaxf(mx, redm[i]);
    float e0 = __expf(a0 - mx), e1 = __expf(a1 - mx);
    float s = e0 + e1;
#pragma unroll
    for (int off = 1; off < 64; off <<= 1) s += __shfl_xor(s, off);
    if (lane == 0) reds[wid] = s;
    __syncthreads();
    float tot = 0.f;
#pragma unroll
    for (int i = 0; i < 16; ++i) tot += reds[i];
    float inv = 1.0f / tot;
    out[b * 2048 + t] = e0 * inv;
    out[b * 2048 + 1024 + t] = e1 * inv;
}

// ---------------------------------------------------------------------------
extern "C" void kernel_launch(void* const* d_in, const int* in_sizes, int n_in,
                              void* d_out, int out_size, void* d_ws, size_t ws_size,
                              hipStream_t stream) {
    const float* query = (const float*)d_in[0];
    const float* value = (const float*)d_in[1];
    const int*   mask  = (const int*)d_in[2];
    const float* Wq    = (const float*)d_in[3];
    const float* bq    = (const float*)d_in[4];
    const float* Wv    = (const float*)d_in[5];
    const float* wv    = (const float*)d_in[6];

    char* ws = (char*)d_ws;
    f16*   BP    = (f16*)(ws + WS_BP);
    float* hq    = (float*)(ws + WS_HQ);
    float* lpart = (float*)(ws + WS_LP);
    float* out   = (float*)d_out;

    (void)hipMemsetAsync(hq, 0, BB * HH * sizeof(float), stream);
    pack_wv<<<(KK * HH) / 256, 256, 0, stream>>>(Wv, BP);
    hq_kernel<<<dim3(16, BB), 256, 0, stream>>>(query, Wq, bq, hq);
    fused_main<<<4096, 256, 0, stream>>>(value, BP, hq, wv, lpart);
    softmax_kernel<<<BB, 1024, 0, stream>>>(lpart, mask, out);
}

// Round 7
// 309.837 us; speedup vs baseline: 1.8560x; 1.8560x over previous
//
#include <hip/hip_runtime.h>
#include <hip/hip_bf16.h>
#include <hip/hip_fp16.h>

typedef _Float16 f16;
typedef _Float16 f16x8 __attribute__((ext_vector_type(8)));
typedef float f32x16 __attribute__((ext_vector_type(16)));
typedef unsigned int u32;

// Problem sizes (fixed)
#define BB 32
#define SS 2048
#define HH 1024
#define KK 1024

// ws layout (bytes)
#define WS_BP 0                            // packed Wv fp16: 2 MB
#define WS_HQ (2u*1024u*1024u)             // hq fp32: 32*1024*4 = 128 KB
#define WS_LP (WS_HQ + 131072u)            // logits partials: 4*32*2048*4 = 1 MB

__device__ __forceinline__ float tanh_f(float x) {
    // tanh(x) = 1 - 2/(e^{2x}+1); safe at +/-inf of exp
    float e = __expf(2.0f * x);
    return 1.0f - 2.0f * __builtin_amdgcn_rcpf(e + 1.0f);
}

__device__ __forceinline__ void gload_lds16(const void* g, void* l) {
    __builtin_amdgcn_global_load_lds(
        (const __attribute__((address_space(1))) u32*)g,
        (__attribute__((address_space(3))) u32*)l, 16, 0, 0);
}

// fp32x8 -> fp16x8 cvt + 16B LDS store
__device__ __forceinline__ void write_a16(char* dst, int off, float4 va, float4 vb) {
    union { f16 h[8]; uint4 u; } pk;
    pk.h[0] = (f16)va.x; pk.h[1] = (f16)va.y; pk.h[2] = (f16)va.z; pk.h[3] = (f16)va.w;
    pk.h[4] = (f16)vb.x; pk.h[5] = (f16)vb.y; pk.h[6] = (f16)vb.z; pk.h[7] = (f16)vb.w;
    *(uint4*)(dst + off) = pk.u;
}

// ---------------------------------------------------------------------------
// Pack Wv [k][n] fp32 -> fragment-ordered fp16 for mfma_f32_32x32x16_f16 B-operand,
// grouped so each (N-block, BK=64 K-tile) slice is one contiguous 32 KB chunk:
// BP[ntb(4)][kit(16)][ntl(8)][ksl(4)][lane(64)][j(8)]
// frag layout: B[k][n], lane l: n = l&31, k = ks*16 + (l>>5)*8 + j
__global__ void pack_wv(const float* __restrict__ Wv, f16* __restrict__ BP) {
    int i = blockIdx.x * 256 + threadIdx.x;   // i = k*1024 + n
    int k = i >> 10, n = i & 1023;
    float v = Wv[i];
    int ntb = n >> 8;              // N-block (256 cols)
    int ntl = (n >> 5) & 7;        // local 32-col tile
    int kit = k >> 6;              // K-tile (BK=64)
    int ksl = (k >> 4) & 3;        // local k-step
    int lane = ((k >> 3) & 1) * 32 + (n & 31);
    int j = k & 7;
    BP[(((((ntb * 16 + kit) * 8 + ntl) * 4 + ksl) * 64 + lane) * 8) + j] = (f16)v;
}

// ---------------------------------------------------------------------------
// hq = query @ Wq + bq  (fp32). K split 4 ways, atomicAdd combine.
__global__ void hq_kernel(const float* __restrict__ query, const float* __restrict__ Wq,
                          const float* __restrict__ bq, float* __restrict__ hq) {
    int b = blockIdx.y;
    int h = (blockIdx.x & 3) * 256 + threadIdx.x;
    int v0 = (blockIdx.x >> 2) * 256;
    float acc = 0.f;
#pragma unroll 8
    for (int v = 0; v < 256; ++v)
        acc += query[b * 1024 + v0 + v] * Wq[(v0 + v) * 1024 + h];
    if (v0 == 0) acc += bq[h];
    atomicAdd(&hq[b * 1024 + h], acc);
}

// ---------------------------------------------------------------------------
// Fused 256x256x(K=1024) GEMM tile + tanh(hq+hv)·w row-reduction.
// m201-style 4-phase-per-K-tile schedule: per phase {6 conflict-free ds_read
// (fragment-ordered LDS) | p0: issue next-tile 4 B-gload_lds + 8 A-reg loads |
// barrier | setprio(1) 8 MFMA setprio(0) | barrier}; ONE vmcnt(0) per K-tile
// at the tail (issue-to-wait ~4 phases) where A regs are cvt'd+written to the
// next buffer. 8 waves (2wr x 4wc), wave tile 128x64, acc 128 VGPR, 1 block/CU.
// LDS 128 KB: A dbuf 2x32KB at 0 (frag-ordered [wrblk*4+ ... ][ks][lane][j]),
//             B dbuf 2x32KB at 65536 (frag-ordered).
__launch_bounds__(512, 2)
__global__ void fused_main(const float* __restrict__ value, const f16* __restrict__ BP,
                           const float* __restrict__ hq, const float* __restrict__ wvec,
                           float* __restrict__ lpart) {
    extern __shared__ char smem[];

    int bid = blockIdx.x;
    int tile = (bid & 7) * 128 + (bid >> 3);   // XCD-chunked swizzle (1024 % 8 == 0)
    int Mt = tile >> 2, ntb = tile & 3;        // 4 N-blocks of one M-tile co-XCD
    int m0 = Mt << 8;                          // 256 rows
    int b = m0 >> 11, s0 = m0 & 2047;

    int tid = threadIdx.x;
    int w = tid >> 6, l = tid & 63;
    int wr = w >> 2, wc = w & 3;
    int l31 = l & 31, lg = l >> 5;

    // ---- A staging: thread t covers row t>>1, k-half (t&1)*32 (32 floats)
    int arow = tid >> 1;
    const float* aga = value + (size_t)(m0 + arow) * 1024 + (tid & 1) * 32;
    // fragment-ordered write offsets: elem(row,k) -> [(row>>5)*4 + (k>>4)][((k>>3)&1)*32 + (row&31)]
    int aw_off[4];
#pragma unroll
    for (int q2 = 0; q2 < 4; ++q2)
        aw_off[q2] = ((tid >> 6) * 4 + (tid & 1) * 2 + (q2 >> 1)) * 1024
                   + (((q2 & 1) * 32 + ((tid >> 1) & 31)) << 4);

    // ---- B global base for this block (16 K-tile chunks of 32 KB)
    const char* bgb = (const char*)BP + (size_t)ntb * (16u * 32768u);

    // ---- fragment read offsets (conflict-free: lane*16 contiguous)
    int a_off[4];
#pragma unroll
    for (int mt = 0; mt < 4; ++mt)
        a_off[mt] = (wr * 4 + mt) * 4096 + l * 16;   // + ks*1024
    int b_off[2];
#pragma unroll
    for (int nt = 0; nt < 2; ++nt)
        b_off[nt] = (wc * 2 + nt) * 4096 + l * 16;   // + ks*1024

    const f32x16 fzero = {};
    f32x16 acc[4][2];
#pragma unroll
    for (int mt = 0; mt < 4; ++mt)
#pragma unroll
        for (int nt = 0; nt < 2; ++nt) acc[mt][nt] = fzero;

    float4 ar[8];   // A register staging (next K-tile)

    // ---- prologue: stage K-tile 0 (B -> B0 via gload_lds, A -> regs -> A0)
    {
#pragma unroll
        for (int i = 0; i < 4; ++i)
            gload_lds16(bgb + i * 8192 + tid * 16, smem + 65536 + i * 8192 + tid * 16);
        const float4* ap = (const float4*)aga;
#pragma unroll
        for (int q = 0; q < 8; ++q) ar[q] = ap[q];
#pragma unroll
        for (int q2 = 0; q2 < 4; ++q2)
            write_a16(smem, aw_off[q2], ar[2 * q2], ar[2 * q2 + 1]);
        asm volatile("s_waitcnt vmcnt(0) lgkmcnt(0)" ::: "memory");
        __builtin_amdgcn_s_barrier();
    }

    // ---- main loop: 16 K-tiles x 4 phases
#pragma unroll 1
    for (int kt = 0; kt < 16; ++kt) {
        const char* Ac = smem + (kt & 1) * 32768;
        const char* Bc = smem + 65536 + (kt & 1) * 32768;
        char* An = smem + ((kt + 1) & 1) * 32768;
        char* Bn = smem + 65536 + ((kt + 1) & 1) * 32768;

#pragma unroll
        for (int p = 0; p < 4; ++p) {
            f16x8 av[4], bv[2];
#pragma unroll
            for (int mt = 0; mt < 4; ++mt)
                av[mt] = *(const f16x8*)(Ac + a_off[mt] + p * 1024);
#pragma unroll
            for (int nt = 0; nt < 2; ++nt)
                bv[nt] = *(const f16x8*)(Bc + b_off[nt] + p * 1024);

            if (p == 0 && kt < 15) {
                // issue ALL next-tile loads here: 4 phases of cover before the
                // single vmcnt(0) at the K-tile tail
                const char* bs = bgb + (size_t)(kt + 1) * 32768;
#pragma unroll
                for (int i = 0; i < 4; ++i)
                    gload_lds16(bs + i * 8192 + tid * 16, Bn + i * 8192 + tid * 16);
                const float4* ap = (const float4*)(aga + (kt + 1) * 64);
#pragma unroll
                for (int q = 0; q < 8; ++q) ar[q] = ap[q];
            }

            __builtin_amdgcn_s_barrier();
            __builtin_amdgcn_sched_barrier(0);
            __builtin_amdgcn_s_setprio(1);
#pragma unroll
            for (int mt = 0; mt < 4; ++mt)
#pragma unroll
                for (int nt = 0; nt < 2; ++nt)
                    acc[mt][nt] = __builtin_amdgcn_mfma_f32_32x32x16_f16(
                        av[mt], bv[nt], acc[mt][nt], 0, 0, 0);
            __builtin_amdgcn_s_setprio(0);
            __builtin_amdgcn_s_barrier();
        }

        if (kt < 15) {
            // K-tile tail: retire next-tile loads (B landed in Bn; A in regs),
            // cvt + write A into An. Only full drain in the loop, 4 phases deep.
            asm volatile("s_waitcnt vmcnt(0)" ::: "memory");
#pragma unroll
            for (int q2 = 0; q2 < 4; ++q2)
                write_a16(An, aw_off[q2], ar[2 * q2], ar[2 * q2 + 1]);
            asm volatile("s_waitcnt lgkmcnt(0)" ::: "memory");
            __builtin_amdgcn_s_barrier();
        }
    }

    // ---- epilogue: t = tanh(hq + hv) * w, pair-folded col reduction
    int h0 = ntb * 256 + wc * 64 + l31;   // nt = 0
    int h1 = h0 + 32;                     // nt = 1
    float hq0 = hq[b * 1024 + h0], hq1 = hq[b * 1024 + h1];
    float w0 = wvec[h0], w1 = wvec[h1];

    float* part = (float*)smem;   // 4 KB [wc(4)][row(256)] in dead A0 region
#pragma unroll
    for (int mt = 0; mt < 4; ++mt) {
#pragma unroll
        for (int i = 0; i < 8; ++i) {
            float pa = tanh_f(hq0 + acc[mt][0][2 * i]) * w0
                     + tanh_f(hq1 + acc[mt][1][2 * i]) * w1;
            float pb = tanh_f(hq0 + acc[mt][0][2 * i + 1]) * w0
                     + tanh_f(hq1 + acc[mt][1][2 * i + 1]) * w1;
            float ea = __shfl_xor(pa, 1), eb = __shfl_xor(pb, 1);
            float g = (l & 1) ? (pb + eb) : (pa + ea);
            g += __shfl_xor(g, 2); g += __shfl_xor(g, 4);
            g += __shfl_xor(g, 8); g += __shfl_xor(g, 16);
            if (l31 < 2) {
                int r = 2 * i + (l31 & 1);
                int row = wr * 128 + mt * 32 + (r & 3) + ((r >> 2) << 3) + (lg << 2);
                part[wc * 256 + row] = g;
            }
        }
    }
    __syncthreads();
    if (tid < 256) {
        float s = part[tid] + part[256 + tid] + part[512 + tid] + part[768 + tid];
        lpart[((size_t)ntb * 32 + b) * 2048 + s0 + tid] = s;
    }
}

// ---------------------------------------------------------------------------
// Masked softmax over S=2048 per b, summing the 4 N-block logit partials.
__global__ void softmax_kernel(const float* __restrict__ lp, const int* __restrict__ mask,
                               float* __restrict__ out) {
    __shared__ float redm[16];
    __shared__ float reds[16];
    const int P = 32 * 2048;
    int b = blockIdx.x, t = threadIdx.x;
    int wid = t >> 6, lane = t & 63;
    int i0 = b * 2048 + t, i1 = i0 + 1024;
    float l0 = lp[i0] + lp[P + i0] + lp[2 * P + i0] + lp[3 * P + i0];
    float l1 = lp[i1] + lp[P + i1] + lp[2 * P + i1] + lp[3 * P + i1];
    float a0 = mask[i0] ? l0 : -1e9f;
    float a1 = mask[i1] ? l1 : -1e9f;
    float mx = fmaxf(a0, a1);
#pragma unroll
    for (int off = 1; off < 64; off <<= 1) mx = fmaxf(mx, __shfl_xor(mx, off));
    if (lane == 0) redm[wid] = mx;
    __syncthreads();
    mx = redm[0];
#pragma unroll
    for (int i = 1; i < 16; ++i) mx = fmaxf(mx, redm[i]);
    float e0 = __expf(a0 - mx), e1 = __expf(a1 - mx);
    float s = e0 + e1;
#pragma unroll
    for (int off = 1; off < 64; off <<= 1) s += __shfl_xor(s, off);
    if (lane == 0) reds[wid] = s;
    __syncthreads();
    float tot = 0.f;
#pragma unroll
    for (int i = 0; i < 16; ++i) tot += reds[i];
    float inv = 1.0f / tot;
    out[b * 2048 + t] = e0 * inv;
    out[b * 2048 + 1024 + t] = e1 * inv;
}

// ---------------------------------------------------------------------------
extern "C" void kernel_launch(void* const* d_in, const int* in_sizes, int n_in,
                              void* d_out, int out_size, void* d_ws, size_t ws_size,
                              hipStream_t stream) {
    const float* query = (const float*)d_in[0];
    const float* value = (const float*)d_in[1];
    const int*   mask  = (const int*)d_in[2];
    const float* Wq    = (const float*)d_in[3];
    const float* bq    = (const float*)d_in[4];
    const float* Wv    = (const float*)d_in[5];
    const float* wv    = (const float*)d_in[6];

    char* ws = (char*)d_ws;
    f16*   BP    = (f16*)(ws + WS_BP);
    float* hq    = (float*)(ws + WS_HQ);
    float* lpart = (float*)(ws + WS_LP);
    float* out   = (float*)d_out;

    (void)hipMemsetAsync(hq, 0, BB * HH * sizeof(float), stream);
    pack_wv<<<(KK * HH) / 256, 256, 0, stream>>>(Wv, BP);
    hq_kernel<<<dim3(16, BB), 256, 0, stream>>>(query, Wq, bq, hq);
    fused_main<<<1024, 512, 131072, stream>>>(value, BP, hq, wv, lpart);
    softmax_kernel<<<BB, 1024, 0, stream>>>(lpart, mask, out);
}

// Round 8
// 211.096 us; speedup vs baseline: 2.7241x; 1.4678x over previous
//
#include <hip/hip_runtime.h>
#include <hip/hip_bf16.h>
#include <hip/hip_fp16.h>

typedef _Float16 f16;
typedef _Float16 f16x8 __attribute__((ext_vector_type(8)));
typedef float f32x16 __attribute__((ext_vector_type(16)));
typedef unsigned int u32;

// Problem sizes (fixed)
#define BB 32
#define SS 2048
#define HH 1024
#define KK 1024

// ws layout (bytes)
#define WS_BP 0                            // packed Wv fp16: 2 MB
#define WS_HQ (2u*1024u*1024u)             // hq fp32: 32*1024*4 = 128 KB
#define WS_LP (WS_HQ + 131072u)            // logits partials: 2*32*2048*4 = 512 KB

__device__ __forceinline__ float tanh_f(float x) {
    // tanh(x) = 1 - 2/(e^{2x}+1); safe at +/-inf of exp
    float e = __expf(2.0f * x);
    return 1.0f - 2.0f * __builtin_amdgcn_rcpf(e + 1.0f);
}

// 4 fp32 -> 4 fp16 + 8B LDS store (A-fragment staging)
__device__ __forceinline__ void write_a8(char* dst, int off, float4 v) {
    union { f16 h[4]; uint2 u; } pk;
    pk.h[0] = (f16)v.x; pk.h[1] = (f16)v.y; pk.h[2] = (f16)v.z; pk.h[3] = (f16)v.w;
    *(uint2*)(dst + off) = pk.u;
}

// ---------------------------------------------------------------------------
// Pack Wv [k][n] fp32 -> fragment-ordered fp16 for mfma_f32_32x32x16_f16 B-operand.
// Layout: BP[ntb(2)][kit(32)][w8(8)][ksl(2)][ntl(2)][lane(64)][j(8)]
//   n = ntb*512 + w8*64 + ntl*32 + (lane&31);  k = kit*32 + ksl*16 + (lane>>5)*8 + j
// Each wave's per-iter slice is 4 KB contiguous (4 x 1KB frags), coalesced.
__global__ void pack_wv(const float* __restrict__ Wv, f16* __restrict__ BP) {
    int i = blockIdx.x * 256 + threadIdx.x;   // i = k*1024 + n
    int k = i >> 10, n = i & 1023;
    float v = Wv[i];
    int ntb = n >> 9, w8 = (n >> 6) & 7, ntl = (n >> 5) & 1, nl = n & 31;
    int kit = k >> 5, ksl = (k >> 4) & 1, lg = (k >> 3) & 1, j = k & 7;
    int lane = lg * 32 + nl;
    BP[(((((((size_t)ntb * 32 + kit) * 8 + w8) * 2 + ksl) * 2 + ntl) * 64 + lane) * 8) + j] = (f16)v;
}

// ---------------------------------------------------------------------------
// hq = query @ Wq + bq  (fp32). K split 4 ways, atomicAdd combine.
__global__ void hq_kernel(const float* __restrict__ query, const float* __restrict__ Wq,
                          const float* __restrict__ bq, float* __restrict__ hq) {
    int b = blockIdx.y;
    int h = (blockIdx.x & 3) * 256 + threadIdx.x;
    int v0 = (blockIdx.x >> 2) * 256;
    float acc = 0.f;
#pragma unroll 8
    for (int v = 0; v < 256; ++v)
        acc += query[b * 1024 + v0 + v] * Wq[(v0 + v) * 1024 + h];
    if (v0 == 0) acc += bq[h];
    atomicAdd(&hq[b * 1024 + h], acc);
}

// ---------------------------------------------------------------------------
// Fused 64x512x(K=1024) GEMM tile + tanh(hq+hv)·w row-reduction.
// Each block owns the FULL half-N (512 cols): value is loaded+converted only
// 2x chip-wide (was 4x) -- the cvt VALU tax and A staging halve. A-tile is a
// tiny 4 KB fragment-ordered LDS buffer (dbuf 2x4KB, reg-pipelined 2 deep);
// B is per-wave direct L2->register (fragment-packed, 4x1KB coalesced loads,
// reg double-buffered 1 iter ahead) -- no B LDS, no vmcnt at barriers ever.
// 8 waves (512 thr), wave tile 64x64 (acc 64 VGPR), launch_bounds(512,4)
// -> 2 independent blocks/CU (cross-block overlap covers the tiny A-barrier).
__launch_bounds__(512, 4)
__global__ void fused_main(const float* __restrict__ value, const f16* __restrict__ BP,
                           const float* __restrict__ hq, const float* __restrict__ wvec,
                           float* __restrict__ lpart) {
    __shared__ char Ab0[4096];
    __shared__ char Ab1[4096];
    __shared__ float part[512];               // [w8(8)][row(64)]

    int bid = blockIdx.x;
    int tile = (bid & 7) * 256 + (bid >> 3);   // XCD swizzle (2048 % 8 == 0)
    int Mt = tile >> 1, ntb = tile & 1;        // ntb pair of one Mt co-XCD
    int m0 = Mt << 6;                          // 64 rows
    int b = m0 >> 11, s0 = m0 & 2047;

    int tid = threadIdx.x;
    int w = tid >> 6, l = tid & 63;
    int l31 = l & 31, lg = l >> 5;

    // ---- A staging: thread -> row=tid>>3 (0..63), 4 floats at k0=(tid&7)*4
    int arow = tid >> 3, ak0 = (tid & 7) * 4;
    const float* aga = value + (size_t)(m0 + arow) * 1024 + ak0;
    // frag slot: [mt(row>>5)][ks(k0>>4)][lane=lg*32+row31][j], 8B at j0=(k0&7)
    int aw_off = (((arow >> 5) * 2 + (ak0 >> 4)) * 64 + ((ak0 >> 3) & 1) * 32 + (arow & 31)) * 16
               + (ak0 & 7) * 2;

    // ---- B per-wave global base (frag f = ks*2+ntl at +f*1024; iter at +kit*32768)
    const char* bg = (const char*)BP + (size_t)ntb * 1048576 + (size_t)w * 4096 + (size_t)l * 16;

    const f32x16 fzero = {};
    f32x16 acc[2][2];                          // [mt][ntl]
#pragma unroll
    for (int mt = 0; mt < 2; ++mt)
#pragma unroll
        for (int nt = 0; nt < 2; ++nt) acc[mt][nt] = fzero;

    f16x8 bvA[4], bvB[4];                      // B reg double-buffer
    float4 faA, faB;                           // A reg pipeline (2 deep)

#define MFMA8(AB, BV) do { \
        f16x8 av_[2][2]; \
        _Pragma("unroll") \
        for (int mt = 0; mt < 2; ++mt) \
            _Pragma("unroll") \
            for (int ks = 0; ks < 2; ++ks) \
                av_[mt][ks] = *(const f16x8*)((AB) + (mt * 2 + ks) * 1024 + l * 16); \
        __builtin_amdgcn_s_setprio(1); \
        _Pragma("unroll") \
        for (int ks = 0; ks < 2; ++ks) \
            _Pragma("unroll") \
            for (int mt = 0; mt < 2; ++mt) \
                _Pragma("unroll") \
                for (int nt = 0; nt < 2; ++nt) \
                    acc[mt][nt] = __builtin_amdgcn_mfma_f32_32x32x16_f16( \
                        av_[mt][ks], (BV)[ks * 2 + nt], acc[mt][nt], 0, 0, 0); \
        __builtin_amdgcn_s_setprio(0); \
    } while (0)

    // ---- prologue: A(0)->LDS Ab0; B(0)->bvA; A(1)->faA
    {
        float4 a0 = *(const float4*)aga;
        write_a8(Ab0, aw_off, a0);
#pragma unroll
        for (int f = 0; f < 4; ++f)
            bvA[f] = *(const f16x8*)(bg + f * 1024);
        faA = *(const float4*)(aga + 32);
        asm volatile("s_waitcnt lgkmcnt(0)" ::: "memory");
        __builtin_amdgcn_s_barrier();
    }

    // ---- main loop: 16 x (even t=2tt / odd t=2tt+1), BK=32 each; barriers
    // carry NO vmcnt (B/A global loads stay in flight across them)
#pragma unroll 1
    for (int tt = 0; tt < 16; ++tt) {
        {   // even t = 2tt: compute (Ab0, bvA); load B(t+1)->bvB, A(t+2)->faB
            const char* bs = bg + (size_t)(2 * tt + 1) * 32768;
#pragma unroll
            for (int f = 0; f < 4; ++f) bvB[f] = *(const f16x8*)(bs + f * 1024);
            int xa = 2 * tt + 2; if (xa > 31) xa = 31;
            faB = *(const float4*)(aga + xa * 32);
            MFMA8(Ab0, bvA);
            write_a8(Ab1, aw_off, faA);        // A(t+1), loaded a full iter ago
            asm volatile("s_waitcnt lgkmcnt(0)" ::: "memory");
            __builtin_amdgcn_s_barrier();
        }
        {   // odd t = 2tt+1: compute (Ab1, bvB); load B(t+2)->bvA, A(t+3)->faA
            int xb = 2 * tt + 2; if (xb > 31) xb = 31;
            const char* bs = bg + (size_t)xb * 32768;
#pragma unroll
            for (int f = 0; f < 4; ++f) bvA[f] = *(const f16x8*)(bs + f * 1024);
            int xc = 2 * tt + 3; if (xc > 31) xc = 31;
            faA = *(const float4*)(aga + xc * 32);
            MFMA8(Ab1, bvB);
            if (tt < 15) write_a8(Ab0, aw_off, faB);
            asm volatile("s_waitcnt lgkmcnt(0)" ::: "memory");
            __builtin_amdgcn_s_barrier();
        }
    }
#undef MFMA8

    // ---- epilogue: t = tanh(hq + hv) * w, pair-folded col reduction
    int h0 = ntb * 512 + w * 64 + l31;    // ntl = 0
    int h1 = h0 + 32;                     // ntl = 1
    float hq0 = hq[b * 1024 + h0], hq1 = hq[b * 1024 + h1];
    float w0 = wvec[h0], w1 = wvec[h1];

#pragma unroll
    for (int mt = 0; mt < 2; ++mt) {
#pragma unroll
        for (int i = 0; i < 8; ++i) {
            float pa = tanh_f(hq0 + acc[mt][0][2 * i]) * w0
                     + tanh_f(hq1 + acc[mt][1][2 * i]) * w1;
            float pb = tanh_f(hq0 + acc[mt][0][2 * i + 1]) * w0
                     + tanh_f(hq1 + acc[mt][1][2 * i + 1]) * w1;
            float ea = __shfl_xor(pa, 1), eb = __shfl_xor(pb, 1);
            float g = (l & 1) ? (pb + eb) : (pa + ea);
            g += __shfl_xor(g, 2); g += __shfl_xor(g, 4);
            g += __shfl_xor(g, 8); g += __shfl_xor(g, 16);
            if (l31 < 2) {
                int r = 2 * i + (l31 & 1);
                int row = mt * 32 + (r & 3) + ((r >> 2) << 3) + (lg << 2);
                part[w * 64 + row] = g;
            }
        }
    }
    __syncthreads();
    if (tid < 64) {
        float s = 0.f;
#pragma unroll
        for (int ww = 0; ww < 8; ++ww) s += part[ww * 64 + tid];
        lpart[((size_t)ntb * 32 + b) * 2048 + s0 + tid] = s;
    }
}

// ---------------------------------------------------------------------------
// Masked softmax over S=2048 per b, summing the 2 N-block logit partials.
__global__ void softmax_kernel(const float* __restrict__ lp, const int* __restrict__ mask,
                               float* __restrict__ out) {
    __shared__ float redm[16];
    __shared__ float reds[16];
    const int P = 32 * 2048;
    int b = blockIdx.x, t = threadIdx.x;
    int wid = t >> 6, lane = t & 63;
    int i0 = b * 2048 + t, i1 = i0 + 1024;
    float l0 = lp[i0] + lp[P + i0];
    float l1 = lp[i1] + lp[P + i1];
    float a0 = mask[i0] ? l0 : -1e9f;
    float a1 = mask[i1] ? l1 : -1e9f;
    float mx = fmaxf(a0, a1);
#pragma unroll
    for (int off = 1; off < 64; off <<= 1) mx = fmaxf(mx, __shfl_xor(mx, off));
    if (lane == 0) redm[wid] = mx;
    __syncthreads();
    mx = redm[0];
#pragma unroll
    for (int i = 1; i < 16; ++i) mx = fmaxf(mx, redm[i]);
    float e0 = __expf(a0 - mx), e1 = __expf(a1 - mx);
    float s = e0 + e1;
#pragma unroll
    for (int off = 1; off < 64; off <<= 1) s += __shfl_xor(s, off);
    if (lane == 0) reds[wid] = s;
    __syncthreads();
    float tot = 0.f;
#pragma unroll
    for (int i = 0; i < 16; ++i) tot += reds[i];
    float inv = 1.0f / tot;
    out[b * 2048 + t] = e0 * inv;
    out[b * 2048 + 1024 + t] = e1 * inv;
}

// ---------------------------------------------------------------------------
extern "C" void kernel_launch(void* const* d_in, const int* in_sizes, int n_in,
                              void* d_out, int out_size, void* d_ws, size_t ws_size,
                              hipStream_t stream) {
    const float* query = (const float*)d_in[0];
    const float* value = (const float*)d_in[1];
    const int*   mask  = (const int*)d_in[2];
    const float* Wq    = (const float*)d_in[3];
    const float* bq    = (const float*)d_in[4];
    const float* Wv    = (const float*)d_in[5];
    const float* wv    = (const float*)d_in[6];

    char* ws = (char*)d_ws;
    f16*   BP    = (f16*)(ws + WS_BP);
    float* hq    = (float*)(ws + WS_HQ);
    float* lpart = (float*)(ws + WS_LP);
    float* out   = (float*)d_out;

    (void)hipMemsetAsync(hq, 0, BB * HH * sizeof(float), stream);
    pack_wv<<<(KK * HH) / 256, 256, 0, stream>>>(Wv, BP);
    hq_kernel<<<dim3(16, BB), 256, 0, stream>>>(query, Wq, bq, hq);
    fused_main<<<2048, 512, 0, stream>>>(value, BP, hq, wv, lpart);
    softmax_kernel<<<BB, 1024, 0, stream>>>(lpart, mask, out);
}